// Round 1
// baseline (203.057 us; speedup 1.0000x reference)
//
#include <hip/hip_runtime.h>
#include <cmath>

// Problem constants (from setup_inputs)
constexpr int B     = 32;
constexpr int L     = 2048;
constexpr int D_CTX = 512;
constexpr int D_Q   = 1024;
constexpr int H     = 256;
constexpr int PRUNE_L = -3;
constexpr int PRUNE_R = 3;
constexpr int W = PRUNE_R - PRUNE_L + 1;  // 7-position window
constexpr int KC = 16;                    // K-chunks for the query matmuls

// ---------------------------------------------------------------------------
// Kernel 1: K-split partials of BOTH query matmuls + zero the arrival
// counters used by kernel 2's fused combine stage.
//   partQ[b,kc,j] = sum_{k in chunk} q[k] * Wq[k,j]
//   part1[b,kc,j] = sum_{k in chunk} q[k] * W1[D_CTX+k,j]
// grid = (KC, B) = 512 blocks, block = 256 (thread j).
// ---------------------------------------------------------------------------
__global__ __launch_bounds__(256) void partial_kernel(
    const float* __restrict__ query,  // [B, D_Q]
    const float* __restrict__ Wq,     // [D_Q, H]
    const float* __restrict__ W1,     // [D_CTX+D_Q, H]
    float* __restrict__ partQ,        // [B, KC, H]
    float* __restrict__ part1,        // [B, KC, H]
    unsigned int* __restrict__ cnt)   // [B] arrival counters for kernel 2
{
    const int kc = blockIdx.x;
    const int b  = blockIdx.y;
    const int j  = threadIdx.x;
    const int k0 = kc * (D_Q / KC);   // 64-k chunk

    // Workspace is poisoned between iterations: re-zero counters every run.
    // Kernel-boundary ordering guarantees visibility before kernel 2 starts.
    if (kc == 0 && j == 0) cnt[b] = 0u;

    __shared__ float q_sh[D_Q / KC];
    if (j < D_Q / KC) q_sh[j] = query[b * D_Q + k0 + j];
    __syncthreads();

    const float* WqR = Wq + (size_t)k0 * H + j;
    const float* W1R = W1 + ((size_t)D_CTX + k0) * H + j;
    float accQ = 0.f, acc1 = 0.f;
#pragma unroll 16
    for (int k = 0; k < D_Q / KC; ++k) {
        const float qk = q_sh[k];
        accQ += qk * WqR[(size_t)k * H];
        acc1 += qk * W1R[(size_t)k * H];
    }
    partQ[((size_t)b * KC + kc) * H + j] = accQ;
    part1[((size_t)b * KC + kc) * H + j] = acc1;
}

// ---------------------------------------------------------------------------
// Kernel 2: fused stats + score + combine.
//   Each of the 7 window blocks per batch redundantly reduces the K-partials
//   (32 KB of L2-hot reads) and recomputes alpha/beta/kappa/center — this is
//   deterministic and identical across the 7 blocks, removing the separate
//   stats kernel. After writing its unnormalized posterior, the LAST block
//   per batch (device-scope atomic counter) normalizes and writes both
//   outputs, removing the separate combine kernel.
// grid = (W, B) = 224 blocks, block = 512.
// ---------------------------------------------------------------------------
__global__ __launch_bounds__(512) void fused_kernel(
    const float* __restrict__ ctx,        // [B, L, D_CTX]
    const float* __restrict__ W1,         // [D_CTX+D_Q, H]; uses rows [0, D_CTX)
    const float* __restrict__ W2,         // [H, 1]
    const float* __restrict__ b2,         // [1]
    const float* __restrict__ kappa_prev, // [B, 1]
    const float* __restrict__ bq,         // [H]
    const float* __restrict__ Ws,         // [H, 3]
    const float* __restrict__ bs,         // [3]
    const float* __restrict__ b1,         // [H]
    const float* __restrict__ partQ,      // [B, KC, H]
    const float* __restrict__ part1,      // [B, KC, H]
    float* __restrict__ post,             // [B, W] unnormalized posterior
    unsigned int* __restrict__ cnt,       // [B] arrival counters (zeroed by K1)
    float* __restrict__ out_e,            // [B, D_CTX]
    float* __restrict__ out_p)            // [B, L]
{
    const int t   = blockIdx.x;  // window slot 0..6
    const int b   = blockIdx.y;
    const int tid = threadIdx.x;

    __shared__ float  h_sh[H];       // 1 KB  tanh(q-proj)
    __shared__ float  qpre_sh[H];    // 1 KB  q-half preact + b1
    __shared__ float  sstat[4];      // alpha, beta, kappa, center
    __shared__ float  c_sh[D_CTX];   // 2 KB  ctx row
    __shared__ float4 part[8][64];   // 8 KB  K-chunk partials
    __shared__ float  red[H];        // 1 KB

    // ---- Phase 1: reduce the 16 K-partials (L2-hot, 16 loads/thread) ----
    if (tid < H) {
        float s = 0.f;
#pragma unroll
        for (int kc = 0; kc < KC; ++kc)
            s += partQ[((size_t)b * KC + kc) * H + tid];
        h_sh[tid] = tanhf(s + bq[tid]);
    } else {
        const int j = tid - H;
        float s = 0.f;
#pragma unroll
        for (int kc = 0; kc < KC; ++kc)
            s += part1[((size_t)b * KC + kc) * H + j];
        qpre_sh[j] = s + b1[j];
    }
    __syncthreads();

    // ---- Phase 2: stats (one wave) ----
    if (tid < 64) {
        float s0 = 0.f, s1 = 0.f, s2 = 0.f;
#pragma unroll
        for (int i = 0; i < 4; ++i) {
            const int   jj = tid + 64 * i;
            const float hv = h_sh[jj];
            s0 += hv * Ws[jj * 3 + 0];
            s1 += hv * Ws[jj * 3 + 1];
            s2 += hv * Ws[jj * 3 + 2];
        }
        for (int off = 32; off > 0; off >>= 1) {
            s0 += __shfl_down(s0, off);
            s1 += __shfl_down(s1, off);
            s2 += __shfl_down(s2, off);
        }
        if (tid == 0) {
            const float alpha = expf(s0 + bs[0]);
            const float beta  = expf(s1 + bs[1]);
            const float kappa = expf(s2 + bs[2]) + kappa_prev[b];
            sstat[0] = alpha;
            sstat[1] = beta;
            sstat[2] = kappa;
            sstat[3] = rintf(kappa);  // round-half-even == jnp.round
        }
    }
    __syncthreads();

    const float alpha  = sstat[0];
    const float beta   = sstat[1];
    const float kappa  = sstat[2];
    const int   center = (int)sstat[3];
    const int   l      = center + PRUNE_L + t;
    const bool  valid  = (l >= 0 && l < L);   // block-uniform

    // ---- Phase 3: MLP score + unnormalized posterior ----
    if (valid) {
        const float4* ctx4 =
            (const float4*)(ctx + ((size_t)b * L + (size_t)l) * D_CTX);
        if (tid < D_CTX / 4) ((float4*)c_sh)[tid] = ctx4[tid];
        __syncthreads();

        const int jg = tid & 63;   // float4 column group
        const int kc = tid >> 6;   // 0..7
        const float4* Wv = (const float4*)W1;
        float4 acc = make_float4(0.f, 0.f, 0.f, 0.f);
        const int k0 = kc * 64;
#pragma unroll 8
        for (int k = k0; k < k0 + 64; ++k) {
            const float  ck = c_sh[k];
            const float4 w  = Wv[k * 64 + jg];
            acc.x += ck * w.x; acc.y += ck * w.y;
            acc.z += ck * w.z; acc.w += ck * w.w;
        }
        part[kc][jg] = acc;
        __syncthreads();
        for (int s = 4; s > 0; s >>= 1) {    // 8-way K-chunk reduce
            if (kc < s) {
                float4 a = part[kc][jg], c = part[kc + s][jg];
                a.x += c.x; a.y += c.y; a.z += c.z; a.w += c.w;
                part[kc][jg] = a;
            }
            __syncthreads();
        }
        if (tid < H) {
            const float pre = ((const float*)part)[tid] + qpre_sh[tid];
            red[tid] = tanhf(pre) * W2[tid];
        }
        __syncthreads();
        for (int s = H / 2; s > 0; s >>= 1) {
            if (tid < s) red[tid] += red[tid + s];
            __syncthreads();
        }
        if (tid == 0) {
            const float score = red[0] + b2[0];
            const float diff  = (float)l - kappa;
            post[b * W + t] = expf(score) * alpha * expf(-beta * diff * diff);
        }
    } else {
        if (tid == 0) post[b * W + t] = 0.0f;
    }

    // ---- Phase 4: last-arriving block per batch does the combine ----
    __shared__ int last;
    if (tid == 0) {
        __threadfence();                          // release: post visible
        const unsigned int old = atomicAdd(&cnt[b], 1u);
        last = (old == (unsigned int)(W - 1));
    }
    __syncthreads();
    if (!last) return;

    __shared__ float p_sh[W];
    __shared__ int   l_sh[W];
    if (tid == 0) {
        __threadfence();                          // acquire side
        float pv[W];
        float sum = 0.f;
        for (int u = 0; u < W; ++u) {
            pv[u] = ((volatile const float*)post)[b * W + u];
            sum += pv[u];
        }
        const float inv = 1.0f / sum;  // sum==0 -> NaN, same as reference
        for (int u = 0; u < W; ++u) {
            p_sh[u] = pv[u] * inv;
            l_sh[u] = center + PRUNE_L + u;
        }
    }
    __syncthreads();

    // p_ctx row: zero-fill (d_out is poisoned) then scatter the window
    float4* prow = (float4*)(out_p + (size_t)b * L);
    prow[tid] = make_float4(0.f, 0.f, 0.f, 0.f);  // 512 thr × 1 float4 = 2048
    __syncthreads();
    if (tid < W) {
        const int ll = l_sh[tid];
        if (ll >= 0 && ll < L) out_p[(size_t)b * L + ll] = p_sh[tid];
    }

    // expected_ctx: 7-term weighted float4 gather (128 float4 = 512 dims)
    if (tid < D_CTX / 4) {
        float4 acc = make_float4(0.f, 0.f, 0.f, 0.f);
#pragma unroll
        for (int u = 0; u < W; ++u) {
            const int ll = l_sh[u];
            if (ll >= 0 && ll < L) {
                const float4 c =
                    ((const float4*)(ctx + ((size_t)b * L + (size_t)ll) * D_CTX))[tid];
                const float p = p_sh[u];
                acc.x += p * c.x; acc.y += p * c.y;
                acc.z += p * c.z; acc.w += p * c.w;
            }
        }
        ((float4*)(out_e + (size_t)b * D_CTX))[tid] = acc;
    }
}

extern "C" void kernel_launch(void* const* d_in, const int* in_sizes, int n_in,
                              void* d_out, int out_size, void* d_ws, size_t ws_size,
                              hipStream_t stream) {
    const float* query      = (const float*)d_in[0];
    const float* ctx        = (const float*)d_in[1];
    const float* kappa_prev = (const float*)d_in[2];
    const float* Wq         = (const float*)d_in[3];
    const float* bq         = (const float*)d_in[4];
    const float* Ws         = (const float*)d_in[5];
    const float* bs         = (const float*)d_in[6];
    const float* W1         = (const float*)d_in[7];
    const float* b1         = (const float*)d_in[8];
    const float* W2         = (const float*)d_in[9];
    const float* b2         = (const float*)d_in[10];

    float* out   = (float*)d_out;
    float* out_e = out;              // [B, D_CTX]
    float* out_p = out + B * D_CTX;  // [B, L]

    // Workspace layout (all 16B-aligned):
    float* partQ = (float*)d_ws;                 // [B, KC, H] = 131072 floats
    float* part1 = partQ + B * KC * H;           // [B, KC, H] = 131072 floats
    float* post  = part1 + B * KC * H;           // [B, W]     = 224 floats (896 B, 16B-mult)
    unsigned int* cnt = (unsigned int*)(post + B * W);  // [B]

    partial_kernel<<<dim3(KC, B), 256, 0, stream>>>(query, Wq, W1,
                                                    partQ, part1, cnt);
    fused_kernel<<<dim3(W, B), 512, 0, stream>>>(ctx, W1, W2, b2,
                                                 kappa_prev, bq, Ws, bs, b1,
                                                 partQ, part1, post, cnt,
                                                 out_e, out_p);
}